// Round 1
// baseline (2201.102 us; speedup 1.0000x reference)
//
#include <hip/hip_runtime.h>

// Swin WindowAttention fused kernel for MI355X (gfx950).
// B_=2048 windows, N=49 tokens, C=512, HEADS=16, HD=32, nW=64 mask windows.
// Strategy: prep kernel casts weights to bf16 in ws; main kernel = 1 block/window,
// 4 waves, each wave owns 4 heads (barrier-free head loop, per-wave LDS scratch),
// then one barrier + cooperative proj GEMM. All GEMMs on mfma_f32_16x16x32_bf16.

#define NT 49
#define DIMC 512
#define HEADS 16
#define HD 32
#define SCALE 0.17677669529663687f
#define LOG2E 1.4426950408889634f

typedef short v8s __attribute__((ext_vector_type(8)));   // 8 bf16 (4 VGPRs)
typedef float v4f __attribute__((ext_vector_type(4)));
typedef unsigned short u16;

#define MFMA(a, b, c) __builtin_amdgcn_mfma_f32_16x16x32_bf16((a), (b), (c), 0, 0, 0)

__device__ __forceinline__ u16 f2b(float f) {   // fp32 -> bf16 RNE
  unsigned u = __float_as_uint(f);
  u += 0x7FFFu + ((u >> 16) & 1u);
  return (u16)(u >> 16);
}

// LDS index helpers (ushort units). XOR swizzles keep every MFMA-fragment
// read/write at <=2-way bank conflict (free per m136).
__device__ __forceinline__ int xb_ix(int tok, int c) {           // [49][512], row stride 1KB
  return ((tok << 9) + c) ^ ((tok & 7) << 3);
}
__device__ __forceinline__ int qk_ix(int base, int tok, int d) { // [64][32], row stride 64B
  return base + (((tok << 5) + d) ^ (((tok >> 1) & 7) << 3));
}
__device__ __forceinline__ int vt_ix(int d, int j) {             // [32][64], row stride 128B
  return 4096 + (((d << 6) + j) ^ ((d & 7) << 3));
}
__device__ __forceinline__ int p_ix(int i, int j) {              // [64][64], overlays Q+K
  return ((i << 6) + j) ^ ((i & 7) << 3);
}

__global__ void prep_weights(const float* __restrict__ qkvw,
                             const float* __restrict__ projw,
                             u16* __restrict__ dst) {
  int t = blockIdx.x * 256 + threadIdx.x;   // 262144 threads, 4 elems each
  int e = t * 4;
  float4 v;
  if (e < 786432) v = *(const float4*)(qkvw + e);
  else            v = *(const float4*)(projw + (e - 786432));
  ushort4 o4 = make_ushort4(f2b(v.x), f2b(v.y), f2b(v.z), f2b(v.w));
  *(ushort4*)(dst + e) = o4;
}

__global__ __launch_bounds__(256, 1) void wattn(
    const float* __restrict__ x, const float* __restrict__ mask,
    const float* __restrict__ qkvb, const float* __restrict__ projb,
    const float* __restrict__ rpb, const u16* __restrict__ wqkv,
    const u16* __restrict__ wproj, float* __restrict__ out) {
  __shared__ u16 xb[NT * DIMC];       // x window, bf16, swizzled   (50176 B)
  __shared__ u16 cx[NT * DIMC];       // ctx (attn output), bf16    (50176 B)
  __shared__ u16 sc_all[4 * 6144];    // per-wave: Q@0 K@2048 VT@4096, P overlays Q+K (49152 B)

  const int tid = threadIdx.x;
  const int lane = tid & 63;
  const int w = tid >> 6;            // wave id 0..3
  const int l15 = lane & 15;
  const int g = lane >> 4;           // 16-lane group 0..3
  const int b = blockIdx.x;

  u16* sc = sc_all + w * 6144;

  // ---- stage x window -> xb (fp32 -> bf16) ----
  {
    const float4* xs = (const float4*)(x + (size_t)b * (NT * DIMC));
    for (int F = tid; F < NT * 128; F += 256) {
      float4 v = xs[F];
      int row = F >> 7;
      int c = (F & 127) << 2;
      int ix = xb_ix(row, c);
      *(ushort4*)&xb[ix] = make_ushort4(f2b(v.x), f2b(v.y), f2b(v.z), f2b(v.w));
    }
  }
  __syncthreads();

  // per-lane A-operand token rows (clamped: rows 49..63 alias row 48; harmless,
  // since j>=49 logits are forced to -inf and i>=49 outputs are never stored)
  int tokA[4];
#pragma unroll
  for (int it = 0; it < 4; ++it) tokA[it] = min(16 * it + l15, NT - 1);

  // relative-position-bias index precompute: idx = ia[i] - jb[j]
  int ia[16];
#pragma unroll
  for (int it = 0; it < 4; ++it)
#pragma unroll
    for (int r = 0; r < 4; ++r) {
      int i = min(16 * it + 4 * g + r, NT - 1);
      ia[it * 4 + r] = 13 * (i / 7) + (i % 7) + 84;
    }
  int jb_[4], jv[4];
#pragma unroll
  for (int jt = 0; jt < 4; ++jt) {
    int j = 16 * jt + l15;
    jv[jt] = (j < NT);
    int jc = min(j, NT - 1);
    jb_[jt] = 13 * (jc / 7) + (jc % 7);
  }
  const float* mrow = mask + (size_t)(b & 63) * (NT * NT);

  // ================= head loop: wave w handles heads w*4 .. w*4+3 =================
  for (int hh = 0; hh < 4; ++hh) {
    const int h = w * 4 + hh;
    const u16* Wq = wqkv + (size_t)(h * HD) * DIMC;
    const u16* Wk = wqkv + (size_t)(512 + h * HD) * DIMC;
    const u16* Wv = wqkv + (size_t)(1024 + h * HD) * DIMC;

    // ---- fused QKV GEMM: Q,K = xb @ W^T (A=xb); V^T = Wv @ xb^T (B=xb) ----
    v4f aQ[4][2], aK[4][2], aV[2][4];
#pragma unroll
    for (int it = 0; it < 4; ++it)
#pragma unroll
      for (int jt = 0; jt < 2; ++jt) { aQ[it][jt] = (v4f){0,0,0,0}; aK[it][jt] = (v4f){0,0,0,0}; }
#pragma unroll
    for (int mt = 0; mt < 2; ++mt)
#pragma unroll
      for (int it = 0; it < 4; ++it) aV[mt][it] = (v4f){0,0,0,0};

    v8s xf[2][4], qf[2][2], kf[2][2], vf[2][2];
    auto LOADK = [&](int bi, int k0) {
      int kk = k0 + 8 * g;
#pragma unroll
      for (int it = 0; it < 4; ++it) xf[bi][it] = *(const v8s*)&xb[xb_ix(tokA[it], kk)];
#pragma unroll
      for (int jt = 0; jt < 2; ++jt) {
        qf[bi][jt] = *(const v8s*)(Wq + (16 * jt + l15) * DIMC + kk);
        kf[bi][jt] = *(const v8s*)(Wk + (16 * jt + l15) * DIMC + kk);
        vf[bi][jt] = *(const v8s*)(Wv + (16 * jt + l15) * DIMC + kk);
      }
    };
    LOADK(0, 0);
#pragma unroll
    for (int ks = 0; ks < 16; ++ks) {
      int cur = ks & 1;
      if (ks < 15) LOADK(cur ^ 1, 32 * (ks + 1));
#pragma unroll
      for (int it = 0; it < 4; ++it)
#pragma unroll
        for (int jt = 0; jt < 2; ++jt) {
          aQ[it][jt] = MFMA(xf[cur][it], qf[cur][jt], aQ[it][jt]);
          aK[it][jt] = MFMA(xf[cur][it], kf[cur][jt], aK[it][jt]);
        }
#pragma unroll
      for (int mt = 0; mt < 2; ++mt)
#pragma unroll
        for (int it = 0; it < 4; ++it)
          aV[mt][it] = MFMA(vf[cur][mt], xf[cur][it], aV[mt][it]);
    }

    // ---- bias add; Q scaled; write Q,K,V^T (bf16) to per-wave LDS ----
#pragma unroll
    for (int jt = 0; jt < 2; ++jt) {
      float bq = qkvb[h * HD + 16 * jt + l15];
      float bk = qkvb[512 + h * HD + 16 * jt + l15];
#pragma unroll
      for (int it = 0; it < 4; ++it)
#pragma unroll
        for (int r = 0; r < 4; ++r) {
          int tok = 16 * it + 4 * g + r;
          sc[qk_ix(0, tok, 16 * jt + l15)] = f2b((aQ[it][jt][r] + bq) * SCALE);
          sc[qk_ix(2048, tok, 16 * jt + l15)] = f2b(aK[it][jt][r] + bk);
        }
    }
#pragma unroll
    for (int mt = 0; mt < 2; ++mt)
#pragma unroll
      for (int r = 0; r < 4; ++r) {
        int d = 16 * mt + 4 * g + r;
        float bv = qkvb[1024 + h * HD + d];
#pragma unroll
        for (int it = 0; it < 4; ++it)
          sc[vt_ix(d, 16 * it + l15)] = f2b(aV[mt][it][r] + bv);
      }

    // ---- S = Q K^T (K-dim = HD = 32: one MFMA per 16x16 tile) ----
    v8s qfr[4], kfr[4];
#pragma unroll
    for (int t = 0; t < 4; ++t) {
      qfr[t] = *(const v8s*)&sc[qk_ix(0, 16 * t + l15, 8 * g)];
      kfr[t] = *(const v8s*)&sc[qk_ix(2048, 16 * t + l15, 8 * g)];
    }
    float sv[4][4][4];   // [it][jt][r] logits
#pragma unroll
    for (int it = 0; it < 4; ++it)
#pragma unroll
      for (int jt = 0; jt < 4; ++jt) {
        v4f acc = (v4f){0,0,0,0};
        acc = MFMA(qfr[it], kfr[jt], acc);
#pragma unroll
        for (int r = 0; r < 4; ++r) sv[it][jt][r] = acc[r];
      }

    // ---- + rel-pos bias + window mask; row softmax (deferred normalization) ----
    float rsum[4][4];
#pragma unroll
    for (int it = 0; it < 4; ++it)
#pragma unroll
      for (int r = 0; r < 4; ++r) {
        int ic = min(16 * it + 4 * g + r, NT - 1);
        const float* mr = mrow + ic * NT;
        float mx = -3e38f;
#pragma unroll
        for (int jt = 0; jt < 4; ++jt) {
          float lg = -3e38f;
          if (jv[jt]) {
            int j = 16 * jt + l15;
            float bias = rpb[(ia[it * 4 + r] - jb_[jt]) * HEADS + h];
            lg = sv[it][jt][r] + bias + mr[j];
          }
          sv[it][jt][r] = lg;
          mx = fmaxf(mx, lg);
        }
        mx = fmaxf(mx, __shfl_xor(mx, 1));
        mx = fmaxf(mx, __shfl_xor(mx, 2));
        mx = fmaxf(mx, __shfl_xor(mx, 4));
        mx = fmaxf(mx, __shfl_xor(mx, 8));
        float sum = 0.f;
#pragma unroll
        for (int jt = 0; jt < 4; ++jt) {
          float p = exp2f((sv[it][jt][r] - mx) * LOG2E);
          sv[it][jt][r] = p;
          sum += p;
        }
        sum += __shfl_xor(sum, 1);
        sum += __shfl_xor(sum, 2);
        sum += __shfl_xor(sum, 4);
        sum += __shfl_xor(sum, 8);
        rsum[it][r] = 1.f / sum;
      }

    // ---- P (unnormalized, bf16) -> LDS, overlaying Q+K (per-wave, DS in-order) ----
#pragma unroll
    for (int it = 0; it < 4; ++it)
#pragma unroll
      for (int jt = 0; jt < 4; ++jt)
#pragma unroll
        for (int r = 0; r < 4; ++r)
          sc[p_ix(16 * it + 4 * g + r, 16 * jt + l15)] = f2b(sv[it][jt][r]);

    // ---- ctx = P @ V  (A = P[i][j], B = V^T[d][j]) ----
    v4f co[4][2];
#pragma unroll
    for (int it = 0; it < 4; ++it)
#pragma unroll
      for (int dt = 0; dt < 2; ++dt) co[it][dt] = (v4f){0,0,0,0};
#pragma unroll
    for (int ks = 0; ks < 2; ++ks) {
      v8s pf[4], vfr[2];
#pragma unroll
      for (int it = 0; it < 4; ++it) pf[it] = *(const v8s*)&sc[p_ix(16 * it + l15, 32 * ks + 8 * g)];
#pragma unroll
      for (int dt = 0; dt < 2; ++dt) vfr[dt] = *(const v8s*)&sc[vt_ix(16 * dt + l15, 32 * ks + 8 * g)];
#pragma unroll
      for (int it = 0; it < 4; ++it)
#pragma unroll
        for (int dt = 0; dt < 2; ++dt)
          co[it][dt] = MFMA(pf[it], vfr[dt], co[it][dt]);
    }

    // ---- normalize, write ctx slice (head h -> cols h*32..h*32+31) ----
#pragma unroll
    for (int it = 0; it < 4; ++it)
#pragma unroll
      for (int r = 0; r < 4; ++r) {
        int tok = 16 * it + 4 * g + r;
        if (tok < NT) {
#pragma unroll
          for (int dt = 0; dt < 2; ++dt)
            cx[xb_ix(tok, h * HD + 16 * dt + l15)] = f2b(co[it][dt][r] * rsum[it][r]);
        }
      }
  }  // head loop

  __syncthreads();

  // ================= proj GEMM: out = cx @ proj_w^T + proj_b; wave w owns cols w*128.. =================
  v4f o[4][8];
#pragma unroll
  for (int it = 0; it < 4; ++it)
#pragma unroll
    for (int jt = 0; jt < 8; ++jt) o[it][jt] = (v4f){0,0,0,0};

  const u16* Wp = wproj + (size_t)(w * 128) * DIMC;
  v8s af[2][4], bfr[2][8];
  auto LOADP = [&](int bi, int k0) {
    int kk = k0 + 8 * g;
#pragma unroll
    for (int it = 0; it < 4; ++it) af[bi][it] = *(const v8s*)&cx[xb_ix(tokA[it], kk)];
#pragma unroll
    for (int jt = 0; jt < 8; ++jt) bfr[bi][jt] = *(const v8s*)(Wp + (16 * jt + l15) * DIMC + kk);
  };
  LOADP(0, 0);
#pragma unroll
  for (int ks = 0; ks < 16; ++ks) {
    int cur = ks & 1;
    if (ks < 15) LOADP(cur ^ 1, 32 * (ks + 1));
#pragma unroll
    for (int it = 0; it < 4; ++it)
#pragma unroll
      for (int jt = 0; jt < 8; ++jt)
        o[it][jt] = MFMA(af[cur][it], bfr[cur][jt], o[it][jt]);
  }

  float* ob = out + (size_t)b * (NT * DIMC) + w * 128;
#pragma unroll
  for (int jt = 0; jt < 8; ++jt) {
    float pb = projb[w * 128 + 16 * jt + l15];
#pragma unroll
    for (int it = 0; it < 4; ++it)
#pragma unroll
      for (int r = 0; r < 4; ++r) {
        int tok = 16 * it + 4 * g + r;
        if (tok < NT) ob[(size_t)tok * DIMC + 16 * jt + l15] = o[it][jt][r] + pb;
      }
  }
}

extern "C" void kernel_launch(void* const* d_in, const int* in_sizes, int n_in,
                              void* d_out, int out_size, void* d_ws, size_t ws_size,
                              hipStream_t stream) {
  const float* x     = (const float*)d_in[0];
  const float* mask  = (const float*)d_in[1];
  const float* qkvw  = (const float*)d_in[2];
  const float* qkvb  = (const float*)d_in[3];
  const float* projw = (const float*)d_in[4];
  const float* projb = (const float*)d_in[5];
  const float* rpb   = (const float*)d_in[6];
  u16* wbf = (u16*)d_ws;   // [0,786432): qkv_w bf16; [786432,1048576): proj_w bf16

  prep_weights<<<1024, 256, 0, stream>>>(qkvw, projw, wbf);
  wattn<<<2048, 256, 0, stream>>>(x, mask, qkvb, projb, rpb,
                                  wbf, wbf + 786432, (float*)d_out);
}

// Round 2
// 2038.714 us; speedup vs baseline: 1.0797x; 1.0797x over previous
//
#include <hip/hip_runtime.h>

// Swin WindowAttention, split-kernel design for MI355X (gfx950).
// prep: weights->bf16. gemm<QKV>: x @ qkv_w^T (m97-style 128x128 MFMA tile,
// global_load_lds for B, inline fp32->bf16 staging for A, XOR-swizzled LDS).
// attn: 1 block/window, 4 waves x 4 heads, Q/K frags straight from global.
// gemm<PROJ>: ctx @ proj_w^T -> fp32 out. Chunked over windows to fit ws.

#define SCALE 0.17677669529663687f
#define LOG2E 1.4426950408889634f

typedef short v8s __attribute__((ext_vector_type(8)));   // 8 bf16
typedef float v4f __attribute__((ext_vector_type(4)));
typedef unsigned short u16;

#define MFMA(a, b, c) __builtin_amdgcn_mfma_f32_16x16x32_bf16((a), (b), (c), 0, 0, 0)

static __device__ __forceinline__ u16 f2b(float f) {   // fp32 -> bf16 RNE
  unsigned u = __float_as_uint(f);
  u += 0x7FFFu + ((u >> 16) & 1u);
  return (u16)(u >> 16);
}

#if defined(__has_builtin)
#if __has_builtin(__builtin_amdgcn_global_load_lds)
#define HAS_GLDS 1
#endif
#endif

// stage 16B: global -> LDS. With the builtin, dest is wave-uniform base +
// lane*16 (hardware); fallback does reg round-trip to the per-thread address.
static __device__ __forceinline__ void stage16(const u16* gp, char* wave_base, char* thr_ptr) {
#ifdef HAS_GLDS
  __builtin_amdgcn_global_load_lds((const __attribute__((address_space(1))) unsigned int*)gp,
                                   (__attribute__((address_space(3))) unsigned int*)wave_base,
                                   16, 0, 0);
#else
  *(v8s*)thr_ptr = *(const v8s*)gp;
#endif
}

__global__ void prep_weights(const float* __restrict__ qkvw,
                             const float* __restrict__ projw,
                             u16* __restrict__ dst) {
  int e = (blockIdx.x * 256 + threadIdx.x) * 4;   // 1048576 elems total
  float4 v;
  if (e < 786432) v = *(const float4*)(qkvw + e);
  else            v = *(const float4*)(projw + (e - 786432));
  *(ushort4*)(dst + e) = make_ushort4(f2b(v.x), f2b(v.y), f2b(v.z), f2b(v.w));
}

// C = A[M,512] @ B[N,512]^T. 128x128 tile, BK=64, 4 waves own 64x64 quadrants.
// LDS tiles [128 rows][64 k] bf16, physical byte p holds logical o = p ^ (((p>>7)&7)<<4)
// (both-sides swizzle -> conflict-free ds_read_b128 fragments).
template<bool QKV>
__global__ __launch_bounds__(256, 3) void gemm(
    const void* __restrict__ Ap, const u16* __restrict__ Bp,
    const float* __restrict__ bias, u16* __restrict__ oQ, u16* __restrict__ oK,
    u16* __restrict__ oV, float* __restrict__ oF, int M) {
  __shared__ u16 As[8192], Bs[8192];
  char* Ab = (char*)As;
  char* Bb = (char*)Bs;
  const int tid = threadIdx.x, lane = tid & 63, w = tid >> 6;
  const int l15 = lane & 15, g = lane >> 4;
  const int wr = w >> 1, wc = w & 1;               // wave quadrant (2x2 of 64x64)
  const int n0 = blockIdx.x << 7, m0 = blockIdx.y << 7;

  // staging map: thread t, chunk i covers physical bytes [i*4096 + t*16, +16)
  int prow[4], pcol[4];
#pragma unroll
  for (int i = 0; i < 4; ++i) {
    int p = (i << 12) + (tid << 4);
    int o = p ^ (((p >> 7) & 7) << 4);
    prow[i] = o >> 7;                              // tile row 0..127
    pcol[i] = (o & 127) >> 1;                      // k element 0..63 (x8)
  }
  int fo[2];                                       // fragment k-chunk byte offset (swizzled)
#pragma unroll
  for (int ks = 0; ks < 2; ++ks) fo[ks] = ((ks * 64 + g * 16) ^ ((l15 & 7) << 4));
  const int arow_b = wr * 8192 + l15 * 128;        // A frag row base (bytes)
  const int brow_b = wc * 8192 + l15 * 128;

  v4f acc[4][4];
#pragma unroll
  for (int a = 0; a < 4; ++a)
#pragma unroll
    for (int b = 0; b < 4; ++b) acc[a][b] = (v4f){0, 0, 0, 0};

  for (int kt = 0; kt < 8; ++kt) {
    const int k0 = kt << 6;
#pragma unroll
    for (int i = 0; i < 4; ++i) {                  // B stage (bf16, async)
      const u16* gp = Bp + (size_t)(n0 + prow[i]) * 512 + k0 + pcol[i];
      stage16(gp, Bb + (i << 12) + (w << 10), Bb + (i << 12) + (tid << 4));
    }
    if constexpr (QKV) {                           // A stage: fp32 -> bf16 via regs
      const float* A = (const float*)Ap;
#pragma unroll
      for (int i = 0; i < 4; ++i) {
        const float* s = A + (size_t)min(m0 + prow[i], M - 1) * 512 + k0 + pcol[i];
        float4 f0 = *(const float4*)s;
        float4 f1 = *(const float4*)(s + 4);
        v8s hv;
        hv[0] = (short)f2b(f0.x); hv[1] = (short)f2b(f0.y);
        hv[2] = (short)f2b(f0.z); hv[3] = (short)f2b(f0.w);
        hv[4] = (short)f2b(f1.x); hv[5] = (short)f2b(f1.y);
        hv[6] = (short)f2b(f1.z); hv[7] = (short)f2b(f1.w);
        *(v8s*)(Ab + (i << 12) + (tid << 4)) = hv;
      }
    } else {                                       // A stage: bf16, async
      const u16* A = (const u16*)Ap;
#pragma unroll
      for (int i = 0; i < 4; ++i) {
        const u16* gp = A + (size_t)min(m0 + prow[i], M - 1) * 512 + k0 + pcol[i];
        stage16(gp, Ab + (i << 12) + (w << 10), Ab + (i << 12) + (tid << 4));
      }
    }
    __syncthreads();
#pragma unroll
    for (int ks = 0; ks < 2; ++ks) {
      v8s a[4], b[4];
#pragma unroll
      for (int it = 0; it < 4; ++it) a[it] = *(const v8s*)(Ab + arow_b + (it << 11) + fo[ks]);
#pragma unroll
      for (int jt = 0; jt < 4; ++jt) b[jt] = *(const v8s*)(Bb + brow_b + (jt << 11) + fo[ks]);
#pragma unroll
      for (int it = 0; it < 4; ++it)
#pragma unroll
        for (int jt = 0; jt < 4; ++jt) acc[it][jt] = MFMA(a[it], b[jt], acc[it][jt]);
    }
    __syncthreads();
  }

  if constexpr (QKV) {
    const int which = blockIdx.x >> 2;             // 0=q 1=k 2=v (128 | 512)
    u16* dst = which == 0 ? oQ : (which == 1 ? oK : oV);
    const float scl = which == 0 ? SCALE : 1.f;
#pragma unroll
    for (int jt = 0; jt < 4; ++jt) {
      int col = n0 + wc * 64 + (jt << 4) + l15;
      float bv = bias[col];
      int h = (col >> 5) & 15, d = col & 31;
#pragma unroll
      for (int it = 0; it < 4; ++it)
#pragma unroll
        for (int r = 0; r < 4; ++r) {
          int m = m0 + wr * 64 + (it << 4) + (g << 2) + r;
          if (m < M) {
            unsigned wl = (unsigned)m / 49u, t = (unsigned)m - wl * 49u;
            dst[(size_t)(((wl << 4) + h) * 49 + t) * 32 + d] = f2b((acc[it][jt][r] + bv) * scl);
          }
        }
    }
  } else {
#pragma unroll
    for (int jt = 0; jt < 4; ++jt) {
      int col = n0 + wc * 64 + (jt << 4) + l15;
      float bv = bias[col];
#pragma unroll
      for (int it = 0; it < 4; ++it)
#pragma unroll
        for (int r = 0; r < 4; ++r) {
          int m = m0 + wr * 64 + (it << 4) + (g << 2) + r;
          if (m < M) oF[(size_t)m * 512 + col] = acc[it][jt][r] + bv;
        }
    }
  }
}

// attention: 1 block = 1 window, wave w handles heads 4w..4w+3 barrier-free.
__global__ __launch_bounds__(256, 3) void attn(
    const u16* __restrict__ Q, const u16* __restrict__ K, const u16* __restrict__ V,
    const float* __restrict__ mask, const float* __restrict__ rpb,
    u16* __restrict__ ctx, int w0) {
  __shared__ u16 sm[4 * 6144];                     // per wave: P[64][64]@0, VT[32][64]@4096
  const int tid = threadIdx.x, lane = tid & 63, w = tid >> 6;
  const int l15 = lane & 15, g = lane >> 4;
  const int wl = blockIdx.x;
  u16* P = sm + w * 6144;
  u16* VT = P + 4096;
  const float* mrow = mask + (size_t)((w0 + wl) & 63) * (49 * 49);

  int tokA[4];
#pragma unroll
  for (int it = 0; it < 4; ++it) tokA[it] = min(16 * it + l15, 48);
  int ia[16];
#pragma unroll
  for (int it = 0; it < 4; ++it)
#pragma unroll
    for (int r = 0; r < 4; ++r) {
      int i = min(16 * it + 4 * g + r, 48);
      ia[it * 4 + r] = 13 * (i / 7) + (i % 7) + 84;
    }
  int jb_[4], jv[4];
#pragma unroll
  for (int jt = 0; jt < 4; ++jt) {
    int j = 16 * jt + l15;
    jv[jt] = (j < 49);
    int jc = min(j, 48);
    jb_[jt] = 13 * (jc / 7) + (jc % 7);
  }

  for (int hh = 0; hh < 4; ++hh) {
    const int h = (w << 2) + hh;
    const size_t hb = (size_t)((wl << 4) + h) * 49 * 32;
    const u16* Qh = Q + hb;
    const u16* Kh = K + hb;
    const u16* Vh = V + hb;

    v8s qfr[4], kfr[4];
#pragma unroll
    for (int t = 0; t < 4; ++t) {
      qfr[t] = *(const v8s*)(Qh + tokA[t] * 32 + (g << 3));
      kfr[t] = *(const v8s*)(Kh + tokA[t] * 32 + (g << 3));
    }
    float sv[4][4][4];
#pragma unroll
    for (int it = 0; it < 4; ++it)
#pragma unroll
      for (int jt = 0; jt < 4; ++jt) {
        v4f s0 = MFMA(qfr[it], kfr[jt], ((v4f){0, 0, 0, 0}));
#pragma unroll
        for (int r = 0; r < 4; ++r) sv[it][jt][r] = s0[r];
      }

    float rsum[4][4];
#pragma unroll
    for (int it = 0; it < 4; ++it)
#pragma unroll
      for (int r = 0; r < 4; ++r) {
        int ic = min(16 * it + 4 * g + r, 48);
        const float* mr = mrow + ic * 49;
        float mx = -3e38f;
#pragma unroll
        for (int jt = 0; jt < 4; ++jt) {
          float lg = -3e38f;
          if (jv[jt]) {
            int j = 16 * jt + l15;
            float bias = rpb[(ia[it * 4 + r] - jb_[jt]) * 16 + h];
            lg = sv[it][jt][r] + bias + mr[j];
          }
          sv[it][jt][r] = lg;
          mx = fmaxf(mx, lg);
        }
        mx = fmaxf(mx, __shfl_xor(mx, 1));
        mx = fmaxf(mx, __shfl_xor(mx, 2));
        mx = fmaxf(mx, __shfl_xor(mx, 4));
        mx = fmaxf(mx, __shfl_xor(mx, 8));
        float sum = 0.f;
#pragma unroll
        for (int jt = 0; jt < 4; ++jt) {
          float p = exp2f((sv[it][jt][r] - mx) * LOG2E);
          sv[it][jt][r] = p;
          sum += p;
        }
        sum += __shfl_xor(sum, 1);
        sum += __shfl_xor(sum, 2);
        sum += __shfl_xor(sum, 4);
        sum += __shfl_xor(sum, 8);
        rsum[it][r] = 1.f / sum;
      }

    // P (unnormalized bf16) -> LDS
#pragma unroll
    for (int it = 0; it < 4; ++it)
#pragma unroll
      for (int jt = 0; jt < 4; ++jt)
#pragma unroll
        for (int r = 0; r < 4; ++r) {
          int i = 16 * it + 4 * g + r;
          P[((i << 6) + 16 * jt + l15) ^ ((i & 7) << 3)] = f2b(sv[it][jt][r]);
        }

    // V -> VT (transposed, swizzled)
#pragma unroll
    for (int it = 0; it < 4; ++it) {
      v8s vv = *(const v8s*)(Vh + tokA[it] * 32 + (g << 3));
      int t = 16 * it + l15;
#pragma unroll
      for (int e = 0; e < 8; ++e) {
        int d = (g << 3) + e;
        VT[(d << 6) + (t ^ ((d & 7) << 3))] = (u16)vv[e];
      }
    }

    v4f co[4][2];
#pragma unroll
    for (int it = 0; it < 4; ++it)
#pragma unroll
      for (int dt = 0; dt < 2; ++dt) co[it][dt] = (v4f){0, 0, 0, 0};
#pragma unroll
    for (int ks = 0; ks < 2; ++ks) {
      int jo = (32 * ks + (g << 3)) ^ ((l15 & 7) << 3);
      v8s pf[4], vf2[2];
#pragma unroll
      for (int it = 0; it < 4; ++it) pf[it] = *(const v8s*)&P[((16 * it + l15) << 6) + jo];
#pragma unroll
      for (int dt = 0; dt < 2; ++dt) vf2[dt] = *(const v8s*)&VT[((16 * dt + l15) << 6) + jo];
#pragma unroll
      for (int it = 0; it < 4; ++it)
#pragma unroll
        for (int dt = 0; dt < 2; ++dt) co[it][dt] = MFMA(pf[it], vf2[dt], co[it][dt]);
    }

#pragma unroll
    for (int it = 0; it < 4; ++it)
#pragma unroll
      for (int r = 0; r < 4; ++r) {
        int tok = 16 * it + 4 * g + r;
        if (tok < 49) {
#pragma unroll
          for (int dt = 0; dt < 2; ++dt)
            ctx[(size_t)(wl * 49 + tok) * 512 + (h << 5) + (dt << 4) + l15] =
                f2b(co[it][dt][r] * rsum[it][r]);
        }
      }
  }
}

extern "C" void kernel_launch(void* const* d_in, const int* in_sizes, int n_in,
                              void* d_out, int out_size, void* d_ws, size_t ws_size,
                              hipStream_t stream) {
  const float* x     = (const float*)d_in[0];
  const float* mask  = (const float*)d_in[1];
  const float* qkvw  = (const float*)d_in[2];
  const float* qkvb  = (const float*)d_in[3];
  const float* projw = (const float*)d_in[4];
  const float* projb = (const float*)d_in[5];
  const float* rpb   = (const float*)d_in[6];
  float* out = (float*)d_out;

  u16* wbf = (u16*)d_ws;                     // 1048576 u16 = 2MB of bf16 weights
  const size_t FIXED_B = 1048576 * 2;
  const size_t PER_W = 200704;               // qkv 3*50176 + ctx 50176 bytes
  size_t avail = ws_size > FIXED_B ? ws_size - FIXED_B : 0;
  int wpc = (int)(avail / PER_W);
  if (wpc < 1) wpc = 1;
  if (wpc > 1024) wpc = 1024;                // cap: keep chunk intermediates L3-resident
  int CH = (2048 + wpc - 1) / wpc;
  wpc = (2048 + CH - 1) / CH;

  u16* qb = wbf + 1048576;
  u16* kb = qb + (size_t)wpc * 25088;
  u16* vb = kb + (size_t)wpc * 25088;
  u16* cb = vb + (size_t)wpc * 25088;

  prep_weights<<<1024, 256, 0, stream>>>(qkvw, projw, wbf);

  for (int c = 0; c < CH; ++c) {
    int w0 = c * wpc;
    int nw = 2048 - w0; if (nw > wpc) nw = wpc;
    if (nw <= 0) break;
    int M = nw * 49;
    int mt = (M + 127) / 128;
    gemm<true><<<dim3(12, mt), 256, 0, stream>>>(
        (const void*)(x + (size_t)w0 * 25088), wbf, qkvb, qb, kb, vb, nullptr, M);
    attn<<<nw, 256, 0, stream>>>(qb, kb, vb, mask, rpb, cb, w0);
    gemm<false><<<dim3(4, mt), 256, 0, stream>>>(
        (const void*)cb, wbf + 786432, projb, nullptr, nullptr, nullptr,
        out + (size_t)w0 * 25088, M);
  }
}